// Round 15
// baseline (568.926 us; speedup 1.0000x reference)
//
#include <hip/hip_runtime.h>
#include <cstdint>

#define NN 10000
#define NE 160000
#define DD 128
#define NL 3

typedef __attribute__((ext_vector_type(8))) __bf16 bf16x8;
typedef __attribute__((ext_vector_type(4))) float f32x4;

__device__ __forceinline__ ushort f2bf(float f) {
  unsigned u = __float_as_uint(f);
  return (ushort)((u + 0x7fffu + ((u >> 16) & 1u)) >> 16);
}
__device__ __forceinline__ float bf2f(ushort s) {
  return __uint_as_float(((unsigned)s) << 16);
}
__device__ __forceinline__ float wsum32(float v) {
  v += __shfl_xor(v, 1); v += __shfl_xor(v, 2); v += __shfl_xor(v, 4);
  v += __shfl_xor(v, 8); v += __shfl_xor(v, 16);
  return v;
}
__device__ __forceinline__ float wsum64(float v) {
  v = wsum32(v); v += __shfl_xor(v, 32); return v;
}
__device__ __forceinline__ void red16_2(float& a, float& b) {
#pragma unroll
  for (int m = 1; m < 16; m <<= 1) { a += __shfl_xor(a, m); b += __shfl_xor(b, m); }
}
__device__ __forceinline__ uint4 ldg16(const ushort* p) { return *(const uint4*)p; }

// ---- 512-thread reg-staged phase: one uint4/thread covers the 8KB chunk ----
#define PH(id, MAXID, AT, ASTR, KK, AS) {                                       \
    if ((id) < (MAXID)) {                                                       \
      ushort* _db = Bb[((id) + 1) & 1];                                         \
      if ((id) & 1) { *(uint4*)(_db + tid * 8) = sa0; }                         \
      else          { *(uint4*)(_db + tid * 8) = sb0; }                         \
    }                                                                           \
    if ((id) + 2 <= (MAXID)) {                                                  \
      if ((id) & 1) { sb0 = ldg16(csrc((id) + 2, tid)); }                       \
      else          { sa0 = ldg16(csrc((id) + 2, tid)); }                       \
    }                                                                           \
    { bf16x8 _a = *(const bf16x8*)((AT) + (r0 + c) * (ASTR) + (KK) * 32 + g * 8); \
      const ushort* _bp = Bb[(id) & 1] + lane * 8;                              \
      __builtin_amdgcn_s_setprio(1);                                            \
      _Pragma("unroll") for (int _t = 0; _t < 8; ++_t)                          \
        AS[_t] = __builtin_amdgcn_mfma_f32_16x16x32_bf16(                       \
            _a, *(const bf16x8*)(_bp + _t * 512), AS[_t], 0, 0, 0);             \
      __builtin_amdgcn_s_setprio(0); }                                          \
    __syncthreads(); }

// ---------- CSR build ----------
__global__ __launch_bounds__(256) void k_hist(const int* __restrict__ dst,
                                              int* __restrict__ deg) {
  int e = blockIdx.x * 256 + threadIdx.x;
  if (e < NE) atomicAdd(&deg[dst[e]], 1);
}

__global__ __launch_bounds__(256) void k_scan(const int* __restrict__ deg,
                                              int* __restrict__ rowptr,
                                              int* __restrict__ cursor) {
  __shared__ int part[256];
  const int t = threadIdx.x;
  const int CH = 40;
  int base = t * CH;
  int s = 0;
  for (int i = 0; i < CH; ++i) {
    int idx = base + i;
    s += (idx < NN) ? deg[idx] : 0;
  }
  part[t] = s;
  __syncthreads();
  for (int off = 1; off < 256; off <<= 1) {
    int v = (t >= off) ? part[t - off] : 0;
    __syncthreads();
    part[t] += v;
    __syncthreads();
  }
  int run = (t == 0) ? 0 : part[t - 1];
  for (int i = 0; i < CH; ++i) {
    int idx = base + i;
    if (idx < NN) {
      rowptr[idx] = run;
      cursor[idx] = run;
      run += deg[idx];
    }
  }
  if (t == 255) rowptr[NN] = part[255];
}

__global__ __launch_bounds__(256) void k_scatter(const int* __restrict__ dst,
                                                 int* __restrict__ cursor,
                                                 int* __restrict__ eids) {
  int e = blockIdx.x * 256 + threadIdx.x;
  if (e < NE) {
    int pos = atomicAdd(&cursor[dst[e]], 1);
    eids[pos] = e;
  }
}

// dstP/srcP in CSR order
__global__ __launch_bounds__(256) void k_permidx(const int* __restrict__ ei,
                                                 const int* __restrict__ perm,
                                                 int* __restrict__ srcP,
                                                 int* __restrict__ dstP) {
  int i = blockIdx.x * 256 + threadIdx.x;
  if (i < NE) {
    int e = perm[i];
    srcP[i] = ei[e];
    dstP[i] = ei[NE + e];
  }
}

// ---------- transpose fp32 [K][N] -> bf16 [N][K] ----------
__global__ __launch_bounds__(256) void k_transp(const float* __restrict__ in,
                                                ushort* __restrict__ out,
                                                int K, int N) {
  __shared__ float T[32][33];
  int k0 = blockIdx.x * 32, n0 = blockIdx.y * 32;
  in += (size_t)blockIdx.z * K * N;
  out += (size_t)blockIdx.z * K * N;
  int tx = threadIdx.x & 31, ty = threadIdx.x >> 5;
#pragma unroll
  for (int r = 0; r < 32; r += 8)
    if (k0 + ty + r < K && n0 + tx < N)
      T[ty + r][tx] = in[(size_t)(k0 + ty + r) * N + n0 + tx];
  __syncthreads();
#pragma unroll
  for (int r = 0; r < 32; r += 8)
    if (n0 + ty + r < N && k0 + tx < K)
      out[(size_t)(n0 + ty + r) * K + k0 + tx] = f2bf(T[tx][ty + r]);
}

// ---------- fused transpose of five 128x128 weights (z = l*5 + which) ------
__global__ __launch_bounds__(256) void k_transp5(
    const float* __restrict__ Wa, const float* __restrict__ Wb,
    const float* __restrict__ Wc, const float* __restrict__ Wd,
    const float* __restrict__ We, ushort* __restrict__ Oa,
    ushort* __restrict__ Ob, ushort* __restrict__ Oc, ushort* __restrict__ Od,
    ushort* __restrict__ Oe) {
  __shared__ float T[32][33];
  int l = blockIdx.z / 5, wsel = blockIdx.z % 5;
  const float* in =
      (wsel == 0 ? Wa : wsel == 1 ? Wb : wsel == 2 ? Wc : wsel == 3 ? Wd : We) +
      (size_t)l * 128 * 128;
  ushort* out =
      (wsel == 0 ? Oa : wsel == 1 ? Ob : wsel == 2 ? Oc : wsel == 3 ? Od : Oe) +
      (size_t)l * 128 * 128;
  int k0 = blockIdx.x * 32, n0 = blockIdx.y * 32;
  int tx = threadIdx.x & 31, ty = threadIdx.x >> 5;
#pragma unroll
  for (int r = 0; r < 32; r += 8)
    T[ty + r][tx] = in[(size_t)(k0 + ty + r) * 128 + n0 + tx];
  __syncthreads();
#pragma unroll
  for (int r = 0; r < 32; r += 8)
    out[(size_t)(n0 + ty + r) * 128 + k0 + tx] = f2bf(T[tx][ty + r]);
}

// ---------- input projections (optional row permutation gather) ----------
template <int K>
__global__ __launch_bounds__(256) void k_inproj(
    const float* __restrict__ inp, const int* __restrict__ perm,
    const float* __restrict__ W, const float* __restrict__ b,
    const float* __restrict__ g, const float* __restrict__ bt,
    float* __restrict__ outF, ushort* __restrict__ outB, int rows) {
  int row = blockIdx.x * 4 + (threadIdx.x >> 6);
  if (row >= rows) return;
  int srow = perm ? perm[row] : row;
  int lane = threadIdx.x & 63;
  float a0 = b[lane], a1 = b[lane + 64];
#pragma unroll
  for (int k = 0; k < K; ++k) {
    float xv = inp[(size_t)srow * K + k];
    a0 = fmaf(xv, W[k * DD + lane], a0);
    a1 = fmaf(xv, W[k * DD + lane + 64], a1);
  }
  float m = wsum64(a0 + a1) * (1.0f / DD);
  float q = wsum64(a0 * a0 + a1 * a1) * (1.0f / DD);
  float rstd = rsqrtf(q - m * m + 1e-5f);
  float o0 = fmaxf((a0 - m) * rstd * g[lane] + bt[lane], 0.0f);
  float o1 = fmaxf((a1 - m) * rstd * g[lane + 64] + bt[lane + 64], 0.0f);
  size_t base = (size_t)row * DD;
  if (outF) { outF[base + lane] = o0; outF[base + lane + 64] = o1; }
  outB[base + lane] = f2bf(o0);
  outB[base + lane + 64] = f2bf(o1);
}

// ---------- node precompute, z-split: z0 Pa=x@Wa+memB, z1 Pb=x@Wb, z2 qb ----
__global__ __launch_bounds__(256) void k_nodepre(
    const ushort* __restrict__ xb, const ushort* __restrict__ memWT,
    const ushort* __restrict__ WqT, const float* __restrict__ memB,
    float* __restrict__ Pa, float* __restrict__ Pb, ushort* __restrict__ qbo) {
  __shared__ __align__(16) ushort Xt[64 * 136];
  __shared__ __align__(16) ushort Bb[4096];
  const int tid = threadIdx.x;
  const int n0 = blockIdx.x * 64;
  const int z = blockIdx.y;
  const ushort* B0 = (z == 0) ? memWT : ((z == 1) ? memWT + 128 : WqT);
  const int bstr = (z < 2) ? 384 : 128;
  uint4 w[2], wn[2];
#pragma unroll
  for (int i = 0; i < 2; ++i) {
    int u = tid + i * 256;
    w[i] = ldg16(B0 + (size_t)(u >> 2) * bstr + (u & 3) * 8);
  }
#pragma unroll
  for (int it = 0; it < 4; ++it) {
    int ch = it * 256 + tid, row = ch >> 4, j = ch & 15;
    int gr = n0 + row; if (gr > NN - 1) gr = NN - 1;
    *(uint4*)(Xt + row * 136 + j * 8) = *(const uint4*)(xb + (size_t)gr * DD + j * 8);
  }
  const int lane = tid & 63, wv = tid >> 6;
  const int c = lane & 15, g = lane >> 4, r0 = wv * 16;
  f32x4 acc[8];
#pragma unroll
  for (int t = 0; t < 8; ++t) acc[t] = (f32x4){0.f, 0.f, 0.f, 0.f};
#pragma unroll
  for (int kk = 0; kk < 4; ++kk) {
    __syncthreads();
#pragma unroll
    for (int i = 0; i < 2; ++i) *(uint4*)(Bb + (tid + i * 256) * 8) = w[i];
    if (kk < 3) {
#pragma unroll
      for (int i = 0; i < 2; ++i) {
        int u = tid + i * 256;
        wn[i] = ldg16(B0 + (size_t)(u >> 2) * bstr + (kk + 1) * 32 + (u & 3) * 8);
      }
    }
    __syncthreads();
    bf16x8 a = *(const bf16x8*)(Xt + (r0 + c) * 136 + kk * 32 + g * 8);
#pragma unroll
    for (int t = 0; t < 8; ++t)
      acc[t] = __builtin_amdgcn_mfma_f32_16x16x32_bf16(
          a, *(const bf16x8*)(Bb + (t * 16 + c) * 32 + g * 8), acc[t], 0, 0, 0);
#pragma unroll
    for (int i = 0; i < 2; ++i) w[i] = wn[i];
  }
  if (z == 0) {
#pragma unroll
    for (int t = 0; t < 8; ++t) {
      float bv = memB[t * 16 + c];
#pragma unroll
      for (int rr = 0; rr < 4; ++rr) {
        int row = n0 + r0 + g * 4 + rr;
        if (row < NN) Pa[(size_t)row * DD + t * 16 + c] = acc[t][rr] + bv;
      }
    }
  } else if (z == 1) {
#pragma unroll
    for (int t = 0; t < 8; ++t)
#pragma unroll
      for (int rr = 0; rr < 4; ++rr) {
        int row = n0 + r0 + g * 4 + rr;
        if (row < NN) Pb[(size_t)row * DD + t * 16 + c] = acc[t][rr];
      }
  } else {
#pragma unroll
    for (int t = 0; t < 8; ++t)
#pragma unroll
      for (int rr = 0; rr < 4; ++rr) {
        int row = n0 + r0 + g * 4 + rr;
        if (row < NN) qbo[(size_t)row * DD + t * 16 + c] = f2bf(acc[t][rr]);
      }
  }
}

// ---------- per-layer edge kernel: 128 edges / 8 waves, 2 blocks/CU --------
__global__ __launch_bounds__(512, 2) void k_edge(
    ushort* __restrict__ ebg, ushort* __restrict__ vbg,
    const float* __restrict__ Pa, const float* __restrict__ Pb,
    const ushort* __restrict__ qb, const int* __restrict__ srcP,
    const int* __restrict__ dstP, const ushort* __restrict__ memWT,
    const float* __restrict__ memG, const float* __restrict__ memBt,
    const ushort* __restrict__ euWT, const float* __restrict__ euB,
    const float* __restrict__ euG, const float* __restrict__ euBt,
    const float* __restrict__ enG, const float* __restrict__ enBt,
    const ushort* __restrict__ WkT, const ushort* __restrict__ WvT,
    float* __restrict__ lg) {
  __shared__ __align__(16) ushort Et[128 * 136];
  __shared__ __align__(16) ushort Mt[128 * 136];
  __shared__ __align__(16) ushort Bb[2][4096];
  const int tid = threadIdx.x;
  const int e0 = blockIdx.x * 128;
  const int lane = tid & 63, wv = tid >> 6;
  const int c = lane & 15, g = lane >> 4, r0 = wv * 16;

  auto csrc = [&](int j, int u) -> const ushort* {
    const ushort* base; int stride, off, kk = j & 3;
    if (j < 4)       { base = memWT; stride = 384; off = 256 + kk * 32; }
    else if (j < 8)  { base = euWT;  stride = 128; off = kk * 32; }
    else if (j < 12) { base = WkT;   stride = 128; off = kk * 32; }
    else             { base = WvT;   stride = 128; off = kk * 32; }
    return base + ((u >> 6) * 16 + (u & 15)) * stride + off + ((u >> 4) & 3) * 8;
  };

  // per-thread fragment-row edge indices (broadcast loads, cheap)
  int dv[4], sv[4];
#pragma unroll
  for (int rr = 0; rr < 4; ++rr) {
    int row = e0 + r0 + g * 4 + rr;
    dv[rr] = dstP[row]; sv[rr] = srcP[row];
  }
  uint4 sa0 = ldg16(csrc(0, tid));
  uint4 sb0 = ldg16(csrc(1, tid));
  // e tile (128 rows, 512 threads)
#pragma unroll
  for (int it = 0; it < 4; ++it) {
    int ch = it * 512 + tid, row = ch >> 4, j = ch & 15;
    *(uint4*)(Et + row * 136 + j * 8) =
        *(const uint4*)(ebg + (size_t)(e0 + row) * DD + j * 8);
  }
  *(uint4*)(Bb[0] + tid * 8) = sa0;
  __syncthreads();

  f32x4 acc[8];

  // ---- G0: pc = e @ Wc ----
#pragma unroll
  for (int t = 0; t < 8; ++t) acc[t] = (f32x4){0.f, 0.f, 0.f, 0.f};
  PH(0, 15, Et, 136, 0, acc)
  PH(1, 15, Et, 136, 1, acc)
  PH(2, 15, Et, 136, 2, acc)
  PH(3, 15, Et, 136, 3, acc)

  // ---- mem = relu(ln(pc + Pa[dst] + Pb[src])) -> Mt ----
  {
    float ps[8][4];
#pragma unroll
    for (int t = 0; t < 8; ++t)
#pragma unroll
      for (int rr = 0; rr < 4; ++rr)
        ps[t][rr] = Pa[(size_t)dv[rr] * DD + t * 16 + c] +
                    Pb[(size_t)sv[rr] * DD + t * 16 + c];
    float s1[4] = {0, 0, 0, 0}, s2[4] = {0, 0, 0, 0};
#pragma unroll
    for (int t = 0; t < 8; ++t)
#pragma unroll
      for (int rr = 0; rr < 4; ++rr) {
        float s = acc[t][rr] + ps[t][rr];
        acc[t][rr] = s; s1[rr] += s; s2[rr] += s * s;
      }
    float mean[4], rstd[4];
#pragma unroll
    for (int rr = 0; rr < 4; ++rr) {
      red16_2(s1[rr], s2[rr]);
      mean[rr] = s1[rr] * (1.f / DD);
      rstd[rr] = rsqrtf(s2[rr] * (1.f / DD) - mean[rr] * mean[rr] + 1e-5f);
    }
#pragma unroll
    for (int t = 0; t < 8; ++t) {
      float gv = memG[t * 16 + c], tv = memBt[t * 16 + c];
#pragma unroll
      for (int rr = 0; rr < 4; ++rr) {
        float o = fmaxf((acc[t][rr] - mean[rr]) * rstd[rr] * gv + tv, 0.f);
        Mt[(r0 + g * 4 + rr) * 136 + t * 16 + c] = f2bf(o);
      }
    }
  }
  __syncthreads();  // Mt visible

  // ---- G1: delta = mem @ euW ----
#pragma unroll
  for (int t = 0; t < 8; ++t) acc[t] = (f32x4){0.f, 0.f, 0.f, 0.f};
  PH(4, 15, Mt, 136, 0, acc)
  PH(5, 15, Mt, 136, 1, acc)
  PH(6, 15, Mt, 136, 2, acc)
  PH(7, 15, Mt, 136, 3, acc)

  // ---- e = ln(e + relu(ln(delta + euB))) in Et ----
  {
    float s1[4] = {0, 0, 0, 0}, s2[4] = {0, 0, 0, 0};
#pragma unroll
    for (int t = 0; t < 8; ++t) {
      float bv = euB[t * 16 + c];
#pragma unroll
      for (int rr = 0; rr < 4; ++rr) {
        float v2 = acc[t][rr] + bv;
        acc[t][rr] = v2; s1[rr] += v2; s2[rr] += v2 * v2;
      }
    }
    float mean[4], rstd[4];
#pragma unroll
    for (int rr = 0; rr < 4; ++rr) {
      red16_2(s1[rr], s2[rr]);
      mean[rr] = s1[rr] * (1.f / DD);
      rstd[rr] = rsqrtf(s2[rr] * (1.f / DD) - mean[rr] * mean[rr] + 1e-5f);
    }
    float t1[4] = {0, 0, 0, 0}, t2[4] = {0, 0, 0, 0};
#pragma unroll
    for (int t = 0; t < 8; ++t) {
      float gv = euG[t * 16 + c], tv = euBt[t * 16 + c];
#pragma unroll
      for (int rr = 0; rr < 4; ++rr) {
        float d = fmaxf((acc[t][rr] - mean[rr]) * rstd[rr] * gv + tv, 0.f);
        float eo = bf2f(Et[(r0 + g * 4 + rr) * 136 + t * 16 + c]);
        float pv = eo + d;
        acc[t][rr] = pv; t1[rr] += pv; t2[rr] += pv * pv;
      }
    }
    float mean3[4], rstd3[4];
#pragma unroll
    for (int rr = 0; rr < 4; ++rr) {
      red16_2(t1[rr], t2[rr]);
      mean3[rr] = t1[rr] * (1.f / DD);
      rstd3[rr] = rsqrtf(t2[rr] * (1.f / DD) - mean3[rr] * mean3[rr] + 1e-5f);
    }
#pragma unroll
    for (int t = 0; t < 8; ++t) {
      float gv = enG[t * 16 + c], tv = enBt[t * 16 + c];
#pragma unroll
      for (int rr = 0; rr < 4; ++rr) {
        float en = (acc[t][rr] - mean3[rr]) * rstd3[rr] * gv + tv;
        Et[(r0 + g * 4 + rr) * 136 + t * 16 + c] = f2bf(en);
      }
    }
  }
  __syncthreads();
#pragma unroll
  for (int it = 0; it < 4; ++it) {
    int ch = it * 512 + tid, row = ch >> 4, j = ch & 15;
    *(uint4*)(ebg + (size_t)(e0 + row) * DD + j * 8) =
        *(const uint4*)(Et + row * 136 + j * 8);
  }

  // q gathers into regs (dst-sorted -> cached); land during G2
  float qvf[8][4];
#pragma unroll
  for (int t = 0; t < 8; ++t)
#pragma unroll
    for (int rr = 0; rr < 4; ++rr)
      qvf[t][rr] = bf2f(qb[(size_t)dv[rr] * DD + t * 16 + c]);

  // ---- G2: kproj = mem @ Wk ----
#pragma unroll
  for (int t = 0; t < 8; ++t) acc[t] = (f32x4){0.f, 0.f, 0.f, 0.f};
  PH(8, 15, Mt, 136, 0, acc)
  PH(9, 15, Mt, 136, 1, acc)
  PH(10, 15, Mt, 136, 2, acc)
  PH(11, 15, Mt, 136, 3, acc)
  // logits
#pragma unroll
  for (int t = 0; t < 8; ++t) {
    float p[4];
#pragma unroll
    for (int rr = 0; rr < 4; ++rr) p[rr] = acc[t][rr] * qvf[t][rr];
#pragma unroll
    for (int m = 1; m < 16; m <<= 1)
#pragma unroll
      for (int rr = 0; rr < 4; ++rr) p[rr] += __shfl_xor(p[rr], m);
    if (c == t) {
#pragma unroll
      for (int rr = 0; rr < 4; ++rr)
        lg[(size_t)(e0 + r0 + g * 4 + rr) * 8 + t] = p[rr] * 0.25f;
    }
  }

  // ---- G3: v = mem @ Wv ----
#pragma unroll
  for (int t = 0; t < 8; ++t) acc[t] = (f32x4){0.f, 0.f, 0.f, 0.f};
  PH(12, 15, Mt, 136, 0, acc)
  PH(13, 15, Mt, 136, 1, acc)
  PH(14, 15, Mt, 136, 2, acc)
  PH(15, 15, Mt, 136, 3, acc)
#pragma unroll
  for (int t = 0; t < 8; ++t)
#pragma unroll
    for (int rr = 0; rr < 4; ++rr)
      Et[(r0 + g * 4 + rr) * 136 + t * 16 + c] = f2bf(acc[t][rr]);
  __syncthreads();
#pragma unroll
  for (int it = 0; it < 4; ++it) {
    int ch = it * 512 + tid, row = ch >> 4, j = ch & 15;
    *(uint4*)(vbg + (size_t)(e0 + row) * DD + j * 8) =
        *(const uint4*)(Et + row * 136 + j * 8);
  }
}

// ---------- fused segment softmax + aggregation (contiguous CSR ranges) ----
__global__ __launch_bounds__(256) void k_aggr(
    const ushort* __restrict__ vbg, float* __restrict__ lg,
    const int* __restrict__ rowptr, float* __restrict__ agg) {
  int node = blockIdx.x * 4 + (threadIdx.x >> 6);
  if (node >= NN) return;
  const int lane = threadIdx.x & 63;
  const int j = lane & 7, h = lane >> 3;
  const int beg = rowptr[node], end = rowptr[node + 1];
  float mx = -3.4e38f;
  for (int i = beg + j; i < end; i += 8)
    mx = fmaxf(mx, lg[(size_t)i * 8 + h]);
  mx = fmaxf(mx, __shfl_xor(mx, 1));
  mx = fmaxf(mx, __shfl_xor(mx, 2));
  mx = fmaxf(mx, __shfl_xor(mx, 4));
  float sm = 0.f;
  for (int i = beg + j; i < end; i += 8) {
    float ex = expf(lg[(size_t)i * 8 + h] - mx);
    lg[(size_t)i * 8 + h] = ex;
    sm += ex;
  }
  sm += __shfl_xor(sm, 1);
  sm += __shfl_xor(sm, 2);
  sm += __shfl_xor(sm, 4);
  float inv = 1.f / (sm + 1e-16f);
  asm volatile("s_waitcnt vmcnt(0)" ::: "memory");
  float acc0 = 0.f, acc1 = 0.f;
  for (int i = beg; i < end; ++i) {
    float w = lg[(size_t)i * 8 + h] * inv;
    ushort2 vv = *(const ushort2*)(vbg + (size_t)i * DD + lane * 2);
    acc0 = fmaf(bf2f(vv.x), w, acc0);
    acc1 = fmaf(bf2f(vv.y), w, acc1);
  }
  *(float2*)(agg + (size_t)node * DD + lane * 2) = make_float2(acc0, acc1);
}

// ---------- merged node kernel: ln(x+vagg@Wo) -> FFN -> ln ----------
__global__ __launch_bounds__(256) void k_node2(
    const float* __restrict__ vagg, const ushort* __restrict__ WoT,
    const float* __restrict__ xres_g, const float* __restrict__ g1,
    const float* __restrict__ bt1, const ushort* __restrict__ W1T,
    const float* __restrict__ b1, const ushort* __restrict__ W2T,
    const float* __restrict__ b2, const float* __restrict__ g2,
    const float* __restrict__ bt2, float* __restrict__ out,
    ushort* __restrict__ outB) {
  __shared__ __align__(16) ushort Xt[64 * 136];
  __shared__ __align__(16) ushort Hs[64 * 264];
  __shared__ __align__(16) ushort Bb[8192];
  const int tid = threadIdx.x;
  const int n0 = blockIdx.x * 64;
  const int lane = tid & 63, wv = tid >> 6;
  const int c = lane & 15, g = lane >> 4, r0 = wv * 16;

  float xres[8][4];
#pragma unroll
  for (int t = 0; t < 8; ++t)
#pragma unroll
    for (int rr = 0; rr < 4; ++rr) {
      int row = n0 + r0 + g * 4 + rr;
      if (row > NN - 1) row = NN - 1;
      xres[t][rr] = xres_g[(size_t)row * DD + t * 16 + c];
    }
  uint4 w[4], wn[4];
#pragma unroll
  for (int i = 0; i < 2; ++i) {
    int u = tid + i * 256;
    w[i] = ldg16(WoT + (size_t)(u >> 2) * 128 + (u & 3) * 8);
  }
#pragma unroll
  for (int it = 0; it < 8; ++it) {
    int ch = it * 256 + tid, row = ch >> 5, j = ch & 31;
    int gr = n0 + row; if (gr > NN - 1) gr = NN - 1;
    float4 vv = *(const float4*)(vagg + (size_t)gr * DD + j * 4);
    ushort4 ov; ov.x = f2bf(vv.x); ov.y = f2bf(vv.y); ov.z = f2bf(vv.z); ov.w = f2bf(vv.w);
    *(ushort4*)(Xt + row * 136 + j * 4) = ov;
  }
  f32x4 acc0[8];
#pragma unroll
  for (int t = 0; t < 8; ++t) acc0[t] = (f32x4){0.f, 0.f, 0.f, 0.f};
  // ---- vagg @ Wo (4 phases) ----
#pragma unroll
  for (int kk = 0; kk < 4; ++kk) {
    __syncthreads();
#pragma unroll
    for (int i = 0; i < 2; ++i) *(uint4*)(Bb + (tid + i * 256) * 8) = w[i];
    if (kk < 3) {
#pragma unroll
      for (int i = 0; i < 2; ++i) {
        int u = tid + i * 256;
        wn[i] = ldg16(WoT + (size_t)(u >> 2) * 128 + (kk + 1) * 32 + (u & 3) * 8);
      }
    }
    __syncthreads();
    bf16x8 a = *(const bf16x8*)(Xt + (r0 + c) * 136 + kk * 32 + g * 8);
#pragma unroll
    for (int t = 0; t < 8; ++t)
      acc0[t] = __builtin_amdgcn_mfma_f32_16x16x32_bf16(
          a, *(const bf16x8*)(Bb + (t * 16 + c) * 32 + g * 8), acc0[t], 0, 0, 0);
#pragma unroll
    for (int i = 0; i < 2; ++i) w[i] = wn[i];
  }
  // ---- LN1 -> xmid ----
  {
    float s1[4] = {0, 0, 0, 0}, s2[4] = {0, 0, 0, 0};
#pragma unroll
    for (int t = 0; t < 8; ++t)
#pragma unroll
      for (int rr = 0; rr < 4; ++rr) {
        float s = acc0[t][rr] + xres[t][rr];
        acc0[t][rr] = s; s1[rr] += s; s2[rr] += s * s;
      }
    float mean[4], rstd[4];
#pragma unroll
    for (int rr = 0; rr < 4; ++rr) {
      red16_2(s1[rr], s2[rr]);
      mean[rr] = s1[rr] * (1.f / DD);
      rstd[rr] = rsqrtf(s2[rr] * (1.f / DD) - mean[rr] * mean[rr] + 1e-5f);
    }
#pragma unroll
    for (int t = 0; t < 8; ++t) {
      float gv = g1[t * 16 + c], tv = bt1[t * 16 + c];
#pragma unroll
      for (int rr = 0; rr < 4; ++rr) {
        float o = (acc0[t][rr] - mean[rr]) * rstd[rr] * gv + tv;
        Xt[(r0 + g * 4 + rr) * 136 + t * 16 + c] = f2bf(o);
      }
    }
  }
  // ---- h = relu(xmid @ W1 + b1) ----
  f32x4 acc16[16];
#pragma unroll
  for (int t = 0; t < 16; ++t) acc16[t] = (f32x4){0.f, 0.f, 0.f, 0.f};
#pragma unroll
  for (int i = 0; i < 4; ++i) {
    int u = tid + i * 256;
    w[i] = ldg16(W1T + (size_t)(u >> 2) * 128 + (u & 3) * 8);
  }
#pragma unroll
  for (int kk = 0; kk < 4; ++kk) {
    __syncthreads();
#pragma unroll
    for (int i = 0; i < 4; ++i) *(uint4*)(Bb + (tid + i * 256) * 8) = w[i];
    if (kk < 3) {
#pragma unroll
      for (int i = 0; i < 4; ++i) {
        int u = tid + i * 256;
        wn[i] = ldg16(W1T + (size_t)(u >> 2) * 128 + (kk + 1) * 32 + (u & 3) * 8);
      }
    }
    __syncthreads();
    bf16x8 a = *(const bf16x8*)(Xt + (r0 + c) * 136 + kk * 32 + g * 8);
#pragma unroll
    for (int t = 0; t < 16; ++t)
      acc16[t] = __builtin_amdgcn_mfma_f32_16x16x32_bf16(
          a, *(const bf16x8*)(Bb + (t * 16 + c) * 32 + g * 8), acc16[t], 0, 0, 0);
#pragma unroll
    for (int i = 0; i < 4; ++i) w[i] = wn[i];
  }
#pragma unroll
  for (int t = 0; t < 16; ++t) {
    float bv = b1[t * 16 + c];
#pragma unroll
    for (int rr = 0; rr < 4; ++rr)
      Hs[(r0 + g * 4 + rr) * 264 + t * 16 + c] = f2bf(fmaxf(acc16[t][rr] + bv, 0.f));
  }
  // ---- h @ W2 (8 phases) ----
#pragma unroll
  for (int t = 0; t < 8; ++t) acc0[t] = (f32x4){0.f, 0.f, 0.f, 0.f};
#pragma unroll
  for (int i = 0; i < 2; ++i) {
    int u = tid + i * 256;
    w[i] = ldg16(W2T + (size_t)(u >> 2) * 256 + (u & 3) * 8);
  }
#pragma unroll
  for (int kk = 0; kk < 8; ++kk) {
    __syncthreads();
#pragma unroll
    for (int i = 0; i < 2; ++i) *(uint4*)(Bb + (tid + i * 256) * 8) = w[i];
    if (kk < 7) {
#pragma unroll
      for (int i = 0; i < 2; ++i) {
        int u = tid + i * 256;
        wn[i] = ldg16(W2T + (size_t)(u >> 2) * 256 + (kk + 1) * 32 + (u & 3) * 8);
      }
    }
    __syncthreads();
    bf16x8 a = *(const bf16x8*)(Hs + (r0 + c) * 264 + kk * 32 + g * 8);
#pragma unroll
    for (int t = 0; t < 8; ++t)
      acc0[t] = __builtin_amdgcn_mfma_f32_16x16x32_bf16(
          a, *(const bf16x8*)(Bb + (t * 16 + c) * 32 + g * 8), acc0[t], 0, 0, 0);
#pragma unroll
    for (int i = 0; i < 2; ++i) w[i] = wn[i];
  }
  // ---- LN2 + stores ----
  {
    float s1[4] = {0, 0, 0, 0}, s2[4] = {0, 0, 0, 0};
#pragma unroll
    for (int t = 0; t < 8; ++t) {
      float bv = b2[t * 16 + c];
#pragma unroll
      for (int rr = 0; rr < 4; ++rr) {
        float s = acc0[t][rr] + bv + bf2f(Xt[(r0 + g * 4 + rr) * 136 + t * 16 + c]);
        acc0[t][rr] = s; s1[rr] += s; s2[rr] += s * s;
      }
    }
    float mean[4], rstd[4];
#pragma unroll
    for (int rr = 0; rr < 4; ++rr) {
      red16_2(s1[rr], s2[rr]);
      mean[rr] = s1[rr] * (1.f / DD);
      rstd[rr] = rsqrtf(s2[rr] * (1.f / DD) - mean[rr] * mean[rr] + 1e-5f);
    }
#pragma unroll
    for (int t = 0; t < 8; ++t) {
      float gv = g2[t * 16 + c], tv = bt2[t * 16 + c];
#pragma unroll
      for (int rr = 0; rr < 4; ++rr) {
        float o = (acc0[t][rr] - mean[rr]) * rstd[rr] * gv + tv;
        int row = n0 + r0 + g * 4 + rr;
        if (row < NN) out[(size_t)row * DD + t * 16 + c] = o;
        Xt[(r0 + g * 4 + rr) * 136 + t * 16 + c] = f2bf(o);
      }
    }
  }
  __syncthreads();
#pragma unroll
  for (int it = 0; it < 4; ++it) {
    int ch = it * 256 + tid, row = ch >> 4, j = ch & 15;
    int gr = n0 + row;
    if (gr < NN)
      *(uint4*)(outB + (size_t)gr * DD + j * 8) = *(const uint4*)(Xt + row * 136 + j * 8);
  }
}

extern "C" void kernel_launch(void* const* d_in, const int* in_sizes, int n_in,
                              void* d_out, int out_size, void* d_ws,
                              size_t ws_size, hipStream_t stream) {
  (void)in_sizes; (void)n_in; (void)out_size; (void)ws_size;
  const float* lane_feats = (const float*)d_in[0];
  const float* edge_attrs = (const float*)d_in[1];
  const int* ei = (const int*)d_in[2];
  const int* dst = ei + NE;
  const float* node_W = (const float*)d_in[3];
  const float* node_b = (const float*)d_in[4];
  const float* node_g = (const float*)d_in[5];
  const float* node_bt = (const float*)d_in[6];
  const float* rpe_W = (const float*)d_in[7];
  const float* rpe_b = (const float*)d_in[8];
  const float* rpe_g = (const float*)d_in[9];
  const float* rpe_bt = (const float*)d_in[10];
  const float* mem_W = (const float*)d_in[11];
  const float* mem_b = (const float*)d_in[12];
  const float* mem_g = (const float*)d_in[13];
  const float* mem_bt = (const float*)d_in[14];
  const float* Wq = (const float*)d_in[15];
  const float* Wk = (const float*)d_in[16];
  const float* Wv = (const float*)d_in[17];
  const float* Wo = (const float*)d_in[18];
  const float* eu_W = (const float*)d_in[19];
  const float* eu_b = (const float*)d_in[20];
  const float* eu_g = (const float*)d_in[21];
  const float* eu_bt = (const float*)d_in[22];
  const float* en_g = (const float*)d_in[23];
  const float* en_bt = (const float*)d_in[24];
  const float* ffn_W1 = (const float*)d_in[25];
  const float* ffn_b1 = (const float*)d_in[26];
  const float* ffn_W2 = (const float*)d_in[27];
  const float* ffn_b2 = (const float*)d_in[28];
  const float* n1_g = (const float*)d_in[29];
  const float* n1_bt = (const float*)d_in[30];
  const float* n2_g = (const float*)d_in[31];
  const float* n2_bt = (const float*)d_in[32];

  char* p = (char*)d_ws;
  auto alloc = [&](size_t bytes) -> char* {
    char* r = p; p += (bytes + 255) & ~(size_t)255; return r;
  };
  float* x = (float*)alloc((size_t)NN * DD * 4);
  float* vagg = (float*)alloc((size_t)NN * DD * 4);
  float* lg = (float*)alloc((size_t)NE * 8 * 4);
  float* Pa = (float*)alloc((size_t)NN * DD * 4);
  float* Pb = (float*)alloc((size_t)NN * DD * 4);
  ushort* qb = (ushort*)alloc((size_t)NN * DD * 2);
  ushort* xb = (ushort*)alloc((size_t)NN * DD * 2);
  ushort* eb = (ushort*)alloc((size_t)NE * DD * 2);
  ushort* vb = (ushort*)alloc((size_t)NE * DD * 2);
  ushort* memWT = (ushort*)alloc((size_t)NL * DD * 384 * 2);
  ushort* euWT = (ushort*)alloc((size_t)NL * DD * DD * 2);
  ushort* WqT = (ushort*)alloc((size_t)NL * DD * DD * 2);
  ushort* WkT = (ushort*)alloc((size_t)NL * DD * DD * 2);
  ushort* WvT = (ushort*)alloc((size_t)NL * DD * DD * 2);
  ushort* WoT = (ushort*)alloc((size_t)NL * DD * DD * 2);
  ushort* W1T = (ushort*)alloc((size_t)NL * 256 * DD * 2);
  ushort* W2T = (ushort*)alloc((size_t)NL * DD * 256 * 2);
  int* deg = (int*)alloc((size_t)NN * 4);
  int* rowptr = (int*)alloc((size_t)(NN + 1) * 4);
  int* cursor = (int*)alloc((size_t)NN * 4);
  int* eids = (int*)alloc((size_t)NE * 4);
  int* srcP = (int*)alloc((size_t)NE * 4);
  int* dstP = (int*)alloc((size_t)NE * 4);

  // CSR build + edge permutation (dst is layer-invariant)
  hipMemsetAsync(deg, 0, (size_t)NN * 4, stream);
  k_hist<<<NE / 256, 256, 0, stream>>>(dst, deg);
  k_scan<<<1, 256, 0, stream>>>(deg, rowptr, cursor);
  k_scatter<<<NE / 256, 256, 0, stream>>>(dst, cursor, eids);
  k_permidx<<<NE / 256, 256, 0, stream>>>(ei, eids, srcP, dstP);

  k_transp<<<dim3(12, 4, NL), 256, 0, stream>>>(mem_W, memWT, 384, DD);
  k_transp5<<<dim3(4, 4, 5 * NL), 256, 0, stream>>>(
      Wq, Wk, Wv, Wo, eu_W, WqT, WkT, WvT, WoT, euWT);
  k_transp<<<dim3(4, 8, NL), 256, 0, stream>>>(ffn_W1, W1T, DD, 256);
  k_transp<<<dim3(8, 4, NL), 256, 0, stream>>>(ffn_W2, W2T, 256, DD);

  k_inproj<10><<<NN / 4, 256, 0, stream>>>(lane_feats, nullptr, node_W, node_b,
                                           node_g, node_bt, x, xb, NN);
  // edge projection gathered into CSR order
  k_inproj<9><<<NE / 4, 256, 0, stream>>>(edge_attrs, eids, rpe_W, rpe_b,
                                          rpe_g, rpe_bt, nullptr, eb, NE);

  const int NB = (NN + 63) / 64;
  for (int l = 0; l < NL; ++l) {
    k_nodepre<<<dim3(NB, 3), 256, 0, stream>>>(
        xb, memWT + (size_t)l * DD * 384, WqT + (size_t)l * DD * DD,
        mem_b + l * DD, Pa, Pb, qb);
    k_edge<<<NE / 128, 512, 0, stream>>>(
        eb, vb, Pa, Pb, qb, srcP, dstP, memWT + (size_t)l * DD * 384,
        mem_g + l * DD, mem_bt + l * DD, euWT + (size_t)l * DD * DD,
        eu_b + l * DD, eu_g + l * DD, eu_bt + l * DD, en_g + l * DD,
        en_bt + l * DD, WkT + (size_t)l * DD * DD, WvT + (size_t)l * DD * DD,
        lg);
    k_aggr<<<(NN + 3) / 4, 256, 0, stream>>>(vb, lg, rowptr, vagg);
    k_node2<<<NB, 256, 0, stream>>>(
        vagg, WoT + (size_t)l * DD * DD, x, n1_g + l * DD, n1_bt + l * DD,
        W1T + (size_t)l * 256 * DD, ffn_b1 + l * 256,
        W2T + (size_t)l * DD * 256, ffn_b2 + l * DD, n2_g + l * DD,
        n2_bt + l * DD, (l == NL - 1) ? (float*)d_out : x, xb);
  }
}

// Round 16
// 505.561 us; speedup vs baseline: 1.1253x; 1.1253x over previous
//
#include <hip/hip_runtime.h>
#include <cstdint>

#define NN 10000
#define NE 160000
#define DD 128
#define NL 3

typedef __attribute__((ext_vector_type(8))) __bf16 bf16x8;
typedef __attribute__((ext_vector_type(4))) float f32x4;

__device__ __forceinline__ ushort f2bf(float f) {
  unsigned u = __float_as_uint(f);
  return (ushort)((u + 0x7fffu + ((u >> 16) & 1u)) >> 16);
}
__device__ __forceinline__ float bf2f(ushort s) {
  return __uint_as_float(((unsigned)s) << 16);
}
__device__ __forceinline__ float wsum32(float v) {
  v += __shfl_xor(v, 1); v += __shfl_xor(v, 2); v += __shfl_xor(v, 4);
  v += __shfl_xor(v, 8); v += __shfl_xor(v, 16);
  return v;
}
__device__ __forceinline__ float wsum64(float v) {
  v = wsum32(v); v += __shfl_xor(v, 32); return v;
}
__device__ __forceinline__ void red16_2(float& a, float& b) {
#pragma unroll
  for (int m = 1; m < 16; m <<= 1) { a += __shfl_xor(a, m); b += __shfl_xor(b, m); }
}
__device__ __forceinline__ uint4 ldg16(const ushort* p) { return *(const uint4*)p; }

// ---- reg-staged lane-linear phase macro (round-5/8 proven) + T5 setprio ----
#define PH(id, MAXID, AT, ASTR, KK, AS) {                                       \
    if ((id) < (MAXID)) {                                                       \
      ushort* _db = Bb[((id) + 1) & 1];                                         \
      if ((id) & 1) { *(uint4*)(_db + tid * 8) = sa0;                           \
                      *(uint4*)(_db + 2048 + tid * 8) = sa1; }                  \
      else          { *(uint4*)(_db + tid * 8) = sb0;                           \
                      *(uint4*)(_db + 2048 + tid * 8) = sb1; }                  \
    }                                                                           \
    if ((id) + 2 <= (MAXID)) {                                                  \
      if ((id) & 1) { sb0 = ldg16(csrc((id) + 2, tid));                         \
                      sb1 = ldg16(csrc((id) + 2, 256 + tid)); }                 \
      else          { sa0 = ldg16(csrc((id) + 2, tid));                         \
                      sa1 = ldg16(csrc((id) + 2, 256 + tid)); }                 \
    }                                                                           \
    { bf16x8 _a = *(const bf16x8*)((AT) + (r0 + c) * (ASTR) + (KK) * 32 + g * 8); \
      const ushort* _bp = Bb[(id) & 1] + lane * 8;                              \
      __builtin_amdgcn_s_setprio(1);                                            \
      _Pragma("unroll") for (int _t = 0; _t < 8; ++_t)                          \
        AS[_t] = __builtin_amdgcn_mfma_f32_16x16x32_bf16(                       \
            _a, *(const bf16x8*)(_bp + _t * 512), AS[_t], 0, 0, 0);             \
      __builtin_amdgcn_s_setprio(0); }                                          \
    __syncthreads(); }

// ---------- CSR build ----------
__global__ __launch_bounds__(256) void k_hist(const int* __restrict__ dst,
                                              int* __restrict__ deg) {
  int e = blockIdx.x * 256 + threadIdx.x;
  if (e < NE) atomicAdd(&deg[dst[e]], 1);
}

__global__ __launch_bounds__(256) void k_scan(const int* __restrict__ deg,
                                              int* __restrict__ rowptr,
                                              int* __restrict__ cursor) {
  __shared__ int part[256];
  const int t = threadIdx.x;
  const int CH = 40;
  int base = t * CH;
  int s = 0;
  for (int i = 0; i < CH; ++i) {
    int idx = base + i;
    s += (idx < NN) ? deg[idx] : 0;
  }
  part[t] = s;
  __syncthreads();
  for (int off = 1; off < 256; off <<= 1) {
    int v = (t >= off) ? part[t - off] : 0;
    __syncthreads();
    part[t] += v;
    __syncthreads();
  }
  int run = (t == 0) ? 0 : part[t - 1];
  for (int i = 0; i < CH; ++i) {
    int idx = base + i;
    if (idx < NN) {
      rowptr[idx] = run;
      cursor[idx] = run;
      run += deg[idx];
    }
  }
  if (t == 255) rowptr[NN] = part[255];
}

__global__ __launch_bounds__(256) void k_scatter(const int* __restrict__ dst,
                                                 int* __restrict__ cursor,
                                                 int* __restrict__ eids) {
  int e = blockIdx.x * 256 + threadIdx.x;
  if (e < NE) {
    int pos = atomicAdd(&cursor[dst[e]], 1);
    eids[pos] = e;
  }
}

// dstP/srcP in CSR order
__global__ __launch_bounds__(256) void k_permidx(const int* __restrict__ ei,
                                                 const int* __restrict__ perm,
                                                 int* __restrict__ srcP,
                                                 int* __restrict__ dstP) {
  int i = blockIdx.x * 256 + threadIdx.x;
  if (i < NE) {
    int e = perm[i];
    srcP[i] = ei[e];
    dstP[i] = ei[NE + e];
  }
}

// ---------- transpose fp32 [K][N] -> bf16 [N][K] ----------
__global__ __launch_bounds__(256) void k_transp(const float* __restrict__ in,
                                                ushort* __restrict__ out,
                                                int K, int N) {
  __shared__ float T[32][33];
  int k0 = blockIdx.x * 32, n0 = blockIdx.y * 32;
  in += (size_t)blockIdx.z * K * N;
  out += (size_t)blockIdx.z * K * N;
  int tx = threadIdx.x & 31, ty = threadIdx.x >> 5;
#pragma unroll
  for (int r = 0; r < 32; r += 8)
    if (k0 + ty + r < K && n0 + tx < N)
      T[ty + r][tx] = in[(size_t)(k0 + ty + r) * N + n0 + tx];
  __syncthreads();
#pragma unroll
  for (int r = 0; r < 32; r += 8)
    if (n0 + ty + r < N && k0 + tx < K)
      out[(size_t)(n0 + ty + r) * K + k0 + tx] = f2bf(T[tx][ty + r]);
}

// ---------- fused transpose of five 128x128 weights (z = l*5 + which) ------
__global__ __launch_bounds__(256) void k_transp5(
    const float* __restrict__ Wa, const float* __restrict__ Wb,
    const float* __restrict__ Wc, const float* __restrict__ Wd,
    const float* __restrict__ We, ushort* __restrict__ Oa,
    ushort* __restrict__ Ob, ushort* __restrict__ Oc, ushort* __restrict__ Od,
    ushort* __restrict__ Oe) {
  __shared__ float T[32][33];
  int l = blockIdx.z / 5, wsel = blockIdx.z % 5;
  const float* in =
      (wsel == 0 ? Wa : wsel == 1 ? Wb : wsel == 2 ? Wc : wsel == 3 ? Wd : We) +
      (size_t)l * 128 * 128;
  ushort* out =
      (wsel == 0 ? Oa : wsel == 1 ? Ob : wsel == 2 ? Oc : wsel == 3 ? Od : Oe) +
      (size_t)l * 128 * 128;
  int k0 = blockIdx.x * 32, n0 = blockIdx.y * 32;
  int tx = threadIdx.x & 31, ty = threadIdx.x >> 5;
#pragma unroll
  for (int r = 0; r < 32; r += 8)
    T[ty + r][tx] = in[(size_t)(k0 + ty + r) * 128 + n0 + tx];
  __syncthreads();
#pragma unroll
  for (int r = 0; r < 32; r += 8)
    out[(size_t)(n0 + ty + r) * 128 + k0 + tx] = f2bf(T[tx][ty + r]);
}

// ---------- input projections (optional row permutation gather) ----------
template <int K>
__global__ __launch_bounds__(256) void k_inproj(
    const float* __restrict__ inp, const int* __restrict__ perm,
    const float* __restrict__ W, const float* __restrict__ b,
    const float* __restrict__ g, const float* __restrict__ bt,
    float* __restrict__ outF, ushort* __restrict__ outB, int rows) {
  int row = blockIdx.x * 4 + (threadIdx.x >> 6);
  if (row >= rows) return;
  int srow = perm ? perm[row] : row;
  int lane = threadIdx.x & 63;
  float a0 = b[lane], a1 = b[lane + 64];
#pragma unroll
  for (int k = 0; k < K; ++k) {
    float xv = inp[(size_t)srow * K + k];
    a0 = fmaf(xv, W[k * DD + lane], a0);
    a1 = fmaf(xv, W[k * DD + lane + 64], a1);
  }
  float m = wsum64(a0 + a1) * (1.0f / DD);
  float q = wsum64(a0 * a0 + a1 * a1) * (1.0f / DD);
  float rstd = rsqrtf(q - m * m + 1e-5f);
  float o0 = fmaxf((a0 - m) * rstd * g[lane] + bt[lane], 0.0f);
  float o1 = fmaxf((a1 - m) * rstd * g[lane + 64] + bt[lane + 64], 0.0f);
  size_t base = (size_t)row * DD;
  if (outF) { outF[base + lane] = o0; outF[base + lane + 64] = o1; }
  outB[base + lane] = f2bf(o0);
  outB[base + lane + 64] = f2bf(o1);
}

// ---------- node precompute, z-split: z0 Pa=x@Wa+memB, z1 Pb=x@Wb, z2 qb ----
__global__ __launch_bounds__(256) void k_nodepre(
    const ushort* __restrict__ xb, const ushort* __restrict__ memWT,
    const ushort* __restrict__ WqT, const float* __restrict__ memB,
    float* __restrict__ Pa, float* __restrict__ Pb, ushort* __restrict__ qbo) {
  __shared__ __align__(16) ushort Xt[64 * 136];
  __shared__ __align__(16) ushort Bb[4096];
  const int tid = threadIdx.x;
  const int n0 = blockIdx.x * 64;
  const int z = blockIdx.y;
  const ushort* B0 = (z == 0) ? memWT : ((z == 1) ? memWT + 128 : WqT);
  const int bstr = (z < 2) ? 384 : 128;
  uint4 w[2], wn[2];
#pragma unroll
  for (int i = 0; i < 2; ++i) {
    int u = tid + i * 256;
    w[i] = ldg16(B0 + (size_t)(u >> 2) * bstr + (u & 3) * 8);
  }
#pragma unroll
  for (int it = 0; it < 4; ++it) {
    int ch = it * 256 + tid, row = ch >> 4, j = ch & 15;
    int gr = n0 + row; if (gr > NN - 1) gr = NN - 1;
    *(uint4*)(Xt + row * 136 + j * 8) = *(const uint4*)(xb + (size_t)gr * DD + j * 8);
  }
  const int lane = tid & 63, wv = tid >> 6;
  const int c = lane & 15, g = lane >> 4, r0 = wv * 16;
  f32x4 acc[8];
#pragma unroll
  for (int t = 0; t < 8; ++t) acc[t] = (f32x4){0.f, 0.f, 0.f, 0.f};
#pragma unroll
  for (int kk = 0; kk < 4; ++kk) {
    __syncthreads();
#pragma unroll
    for (int i = 0; i < 2; ++i) *(uint4*)(Bb + (tid + i * 256) * 8) = w[i];
    if (kk < 3) {
#pragma unroll
      for (int i = 0; i < 2; ++i) {
        int u = tid + i * 256;
        wn[i] = ldg16(B0 + (size_t)(u >> 2) * bstr + (kk + 1) * 32 + (u & 3) * 8);
      }
    }
    __syncthreads();
    bf16x8 a = *(const bf16x8*)(Xt + (r0 + c) * 136 + kk * 32 + g * 8);
#pragma unroll
    for (int t = 0; t < 8; ++t)
      acc[t] = __builtin_amdgcn_mfma_f32_16x16x32_bf16(
          a, *(const bf16x8*)(Bb + (t * 16 + c) * 32 + g * 8), acc[t], 0, 0, 0);
#pragma unroll
    for (int i = 0; i < 2; ++i) w[i] = wn[i];
  }
  if (z == 0) {
#pragma unroll
    for (int t = 0; t < 8; ++t) {
      float bv = memB[t * 16 + c];
#pragma unroll
      for (int rr = 0; rr < 4; ++rr) {
        int row = n0 + r0 + g * 4 + rr;
        if (row < NN) Pa[(size_t)row * DD + t * 16 + c] = acc[t][rr] + bv;
      }
    }
  } else if (z == 1) {
#pragma unroll
    for (int t = 0; t < 8; ++t)
#pragma unroll
      for (int rr = 0; rr < 4; ++rr) {
        int row = n0 + r0 + g * 4 + rr;
        if (row < NN) Pb[(size_t)row * DD + t * 16 + c] = acc[t][rr];
      }
  } else {
#pragma unroll
    for (int t = 0; t < 8; ++t)
#pragma unroll
      for (int rr = 0; rr < 4; ++rr) {
        int row = n0 + r0 + g * 4 + rr;
        if (row < NN) qbo[(size_t)row * DD + t * 16 + c] = f2bf(acc[t][rr]);
      }
  }
}

// ---------- per-layer edge kernel: round-8 structure, 3 blocks/CU ----------
__global__ __launch_bounds__(256, 3) void k_edge(
    ushort* __restrict__ ebg, ushort* __restrict__ vbg,
    const float* __restrict__ Pa, const float* __restrict__ Pb,
    const ushort* __restrict__ qb, const int* __restrict__ srcP,
    const int* __restrict__ dstP, const ushort* __restrict__ memWT,
    const float* __restrict__ memG, const float* __restrict__ memBt,
    const ushort* __restrict__ euWT, const float* __restrict__ euB,
    const float* __restrict__ euG, const float* __restrict__ euBt,
    const float* __restrict__ enG, const float* __restrict__ enBt,
    const ushort* __restrict__ WkT, const ushort* __restrict__ WvT,
    float* __restrict__ lg) {
  __shared__ __align__(16) ushort Et[64 * 136];
  __shared__ __align__(16) ushort Mt[64 * 136];
  __shared__ __align__(16) ushort Bb[2][4096];
  const int tid = threadIdx.x;
  const int e0 = blockIdx.x * 64;
  const int lane = tid & 63, wv = tid >> 6;
  const int c = lane & 15, g = lane >> 4, r0 = wv * 16;

  auto csrc = [&](int j, int u) -> const ushort* {
    const ushort* base; int stride, off, kk = j & 3;
    if (j < 4)       { base = memWT; stride = 384; off = 256 + kk * 32; }
    else if (j < 8)  { base = euWT;  stride = 128; off = kk * 32; }
    else if (j < 12) { base = WkT;   stride = 128; off = kk * 32; }
    else             { base = WvT;   stride = 128; off = kk * 32; }
    return base + ((u >> 6) * 16 + (u & 15)) * stride + off + ((u >> 4) & 3) * 8;
  };

  // per-thread fragment-row edge indices (broadcast loads, cheap)
  int dv[4], sv[4];
#pragma unroll
  for (int rr = 0; rr < 4; ++rr) {
    int row = e0 + r0 + g * 4 + rr;
    dv[rr] = dstP[row]; sv[rr] = srcP[row];
  }
  uint4 sa0 = ldg16(csrc(0, tid)), sa1 = ldg16(csrc(0, 256 + tid));
  uint4 sb0 = ldg16(csrc(1, tid)), sb1 = ldg16(csrc(1, 256 + tid));
  // e tile
#pragma unroll
  for (int it = 0; it < 4; ++it) {
    int ch = it * 256 + tid, row = ch >> 4, j = ch & 15;
    *(uint4*)(Et + row * 136 + j * 8) =
        *(const uint4*)(ebg + (size_t)(e0 + row) * DD + j * 8);
  }
  *(uint4*)(Bb[0] + tid * 8) = sa0;
  *(uint4*)(Bb[0] + 2048 + tid * 8) = sa1;
  __syncthreads();

  f32x4 acc[8];

  // ---- G0: pc = e @ Wc ----
#pragma unroll
  for (int t = 0; t < 8; ++t) acc[t] = (f32x4){0.f, 0.f, 0.f, 0.f};
  PH(0, 15, Et, 136, 0, acc)
  PH(1, 15, Et, 136, 1, acc)
  PH(2, 15, Et, 136, 2, acc)
  PH(3, 15, Et, 136, 3, acc)

  // ---- mem = relu(ln(pc + Pa[dst] + Pb[src])) -> Mt ----
  {
    float ps[8][4];
#pragma unroll
    for (int t = 0; t < 8; ++t)
#pragma unroll
      for (int rr = 0; rr < 4; ++rr)
        ps[t][rr] = Pa[(size_t)dv[rr] * DD + t * 16 + c] +
                    Pb[(size_t)sv[rr] * DD + t * 16 + c];
    float s1[4] = {0, 0, 0, 0}, s2[4] = {0, 0, 0, 0};
#pragma unroll
    for (int t = 0; t < 8; ++t)
#pragma unroll
      for (int rr = 0; rr < 4; ++rr) {
        float s = acc[t][rr] + ps[t][rr];
        acc[t][rr] = s; s1[rr] += s; s2[rr] += s * s;
      }
    float mean[4], rstd[4];
#pragma unroll
    for (int rr = 0; rr < 4; ++rr) {
      red16_2(s1[rr], s2[rr]);
      mean[rr] = s1[rr] * (1.f / DD);
      rstd[rr] = rsqrtf(s2[rr] * (1.f / DD) - mean[rr] * mean[rr] + 1e-5f);
    }
#pragma unroll
    for (int t = 0; t < 8; ++t) {
      float gv = memG[t * 16 + c], tv = memBt[t * 16 + c];
#pragma unroll
      for (int rr = 0; rr < 4; ++rr) {
        float o = fmaxf((acc[t][rr] - mean[rr]) * rstd[rr] * gv + tv, 0.f);
        Mt[(r0 + g * 4 + rr) * 136 + t * 16 + c] = f2bf(o);
      }
    }
  }
  __syncthreads();  // Mt visible

  // ---- G1: delta = mem @ euW ----
#pragma unroll
  for (int t = 0; t < 8; ++t) acc[t] = (f32x4){0.f, 0.f, 0.f, 0.f};
  PH(4, 15, Mt, 136, 0, acc)
  PH(5, 15, Mt, 136, 1, acc)
  PH(6, 15, Mt, 136, 2, acc)
  PH(7, 15, Mt, 136, 3, acc)

  // ---- e = ln(e + relu(ln(delta + euB))) in Et ----
  {
    float s1[4] = {0, 0, 0, 0}, s2[4] = {0, 0, 0, 0};
#pragma unroll
    for (int t = 0; t < 8; ++t) {
      float bv = euB[t * 16 + c];
#pragma unroll
      for (int rr = 0; rr < 4; ++rr) {
        float v2 = acc[t][rr] + bv;
        acc[t][rr] = v2; s1[rr] += v2; s2[rr] += v2 * v2;
      }
    }
    float mean[4], rstd[4];
#pragma unroll
    for (int rr = 0; rr < 4; ++rr) {
      red16_2(s1[rr], s2[rr]);
      mean[rr] = s1[rr] * (1.f / DD);
      rstd[rr] = rsqrtf(s2[rr] * (1.f / DD) - mean[rr] * mean[rr] + 1e-5f);
    }
    float t1[4] = {0, 0, 0, 0}, t2[4] = {0, 0, 0, 0};
#pragma unroll
    for (int t = 0; t < 8; ++t) {
      float gv = euG[t * 16 + c], tv = euBt[t * 16 + c];
#pragma unroll
      for (int rr = 0; rr < 4; ++rr) {
        float d = fmaxf((acc[t][rr] - mean[rr]) * rstd[rr] * gv + tv, 0.f);
        float eo = bf2f(Et[(r0 + g * 4 + rr) * 136 + t * 16 + c]);
        float pv = eo + d;
        acc[t][rr] = pv; t1[rr] += pv; t2[rr] += pv * pv;
      }
    }
    float mean3[4], rstd3[4];
#pragma unroll
    for (int rr = 0; rr < 4; ++rr) {
      red16_2(t1[rr], t2[rr]);
      mean3[rr] = t1[rr] * (1.f / DD);
      rstd3[rr] = rsqrtf(t2[rr] * (1.f / DD) - mean3[rr] * mean3[rr] + 1e-5f);
    }
#pragma unroll
    for (int t = 0; t < 8; ++t) {
      float gv = enG[t * 16 + c], tv = enBt[t * 16 + c];
#pragma unroll
      for (int rr = 0; rr < 4; ++rr) {
        float en = (acc[t][rr] - mean3[rr]) * rstd3[rr] * gv + tv;
        Et[(r0 + g * 4 + rr) * 136 + t * 16 + c] = f2bf(en);
      }
    }
  }
  __syncthreads();
#pragma unroll
  for (int it = 0; it < 4; ++it) {
    int ch = it * 256 + tid, row = ch >> 4, j = ch & 15;
    *(uint4*)(ebg + (size_t)(e0 + row) * DD + j * 8) =
        *(const uint4*)(Et + row * 136 + j * 8);
  }

  // q gathers into regs (dst-sorted -> cached); land during G2
  float qvf[8][4];
#pragma unroll
  for (int t = 0; t < 8; ++t)
#pragma unroll
    for (int rr = 0; rr < 4; ++rr)
      qvf[t][rr] = bf2f(qb[(size_t)dv[rr] * DD + t * 16 + c]);

  // ---- G2: kproj = mem @ Wk ----
#pragma unroll
  for (int t = 0; t < 8; ++t) acc[t] = (f32x4){0.f, 0.f, 0.f, 0.f};
  PH(8, 15, Mt, 136, 0, acc)
  PH(9, 15, Mt, 136, 1, acc)
  PH(10, 15, Mt, 136, 2, acc)
  PH(11, 15, Mt, 136, 3, acc)
  // logits
#pragma unroll
  for (int t = 0; t < 8; ++t) {
    float p[4];
#pragma unroll
    for (int rr = 0; rr < 4; ++rr) p[rr] = acc[t][rr] * qvf[t][rr];
#pragma unroll
    for (int m = 1; m < 16; m <<= 1)
#pragma unroll
      for (int rr = 0; rr < 4; ++rr) p[rr] += __shfl_xor(p[rr], m);
    if (c == t) {
#pragma unroll
      for (int rr = 0; rr < 4; ++rr)
        lg[(size_t)(e0 + r0 + g * 4 + rr) * 8 + t] = p[rr] * 0.25f;
    }
  }

  // ---- G3: v = mem @ Wv ----
#pragma unroll
  for (int t = 0; t < 8; ++t) acc[t] = (f32x4){0.f, 0.f, 0.f, 0.f};
  PH(12, 15, Mt, 136, 0, acc)
  PH(13, 15, Mt, 136, 1, acc)
  PH(14, 15, Mt, 136, 2, acc)
  PH(15, 15, Mt, 136, 3, acc)
#pragma unroll
  for (int t = 0; t < 8; ++t)
#pragma unroll
    for (int rr = 0; rr < 4; ++rr)
      Et[(r0 + g * 4 + rr) * 136 + t * 16 + c] = f2bf(acc[t][rr]);
  __syncthreads();
#pragma unroll
  for (int it = 0; it < 4; ++it) {
    int ch = it * 256 + tid, row = ch >> 4, j = ch & 15;
    *(uint4*)(vbg + (size_t)(e0 + row) * DD + j * 8) =
        *(const uint4*)(Et + row * 136 + j * 8);
  }
}

// ---------- fused segment softmax + aggregation (contiguous CSR ranges) ----
__global__ __launch_bounds__(256) void k_aggr(
    const ushort* __restrict__ vbg, float* __restrict__ lg,
    const int* __restrict__ rowptr, float* __restrict__ agg) {
  int node = blockIdx.x * 4 + (threadIdx.x >> 6);
  if (node >= NN) return;
  const int lane = threadIdx.x & 63;
  const int j = lane & 7, h = lane >> 3;
  const int beg = rowptr[node], end = rowptr[node + 1];
  float mx = -3.4e38f;
  for (int i = beg + j; i < end; i += 8)
    mx = fmaxf(mx, lg[(size_t)i * 8 + h]);
  mx = fmaxf(mx, __shfl_xor(mx, 1));
  mx = fmaxf(mx, __shfl_xor(mx, 2));
  mx = fmaxf(mx, __shfl_xor(mx, 4));
  float sm = 0.f;
  for (int i = beg + j; i < end; i += 8) {
    float ex = expf(lg[(size_t)i * 8 + h] - mx);
    lg[(size_t)i * 8 + h] = ex;
    sm += ex;
  }
  sm += __shfl_xor(sm, 1);
  sm += __shfl_xor(sm, 2);
  sm += __shfl_xor(sm, 4);
  float inv = 1.f / (sm + 1e-16f);
  asm volatile("s_waitcnt vmcnt(0)" ::: "memory");
  float acc0 = 0.f, acc1 = 0.f;
  for (int i = beg; i < end; ++i) {
    float w = lg[(size_t)i * 8 + h] * inv;
    ushort2 vv = *(const ushort2*)(vbg + (size_t)i * DD + lane * 2);
    acc0 = fmaf(bf2f(vv.x), w, acc0);
    acc1 = fmaf(bf2f(vv.y), w, acc1);
  }
  *(float2*)(agg + (size_t)node * DD + lane * 2) = make_float2(acc0, acc1);
}

// ---------- merged node kernel: ln(x+vagg@Wo) -> FFN -> ln ----------
__global__ __launch_bounds__(256) void k_node2(
    const float* __restrict__ vagg, const ushort* __restrict__ WoT,
    const float* __restrict__ xres_g, const float* __restrict__ g1,
    const float* __restrict__ bt1, const ushort* __restrict__ W1T,
    const float* __restrict__ b1, const ushort* __restrict__ W2T,
    const float* __restrict__ b2, const float* __restrict__ g2,
    const float* __restrict__ bt2, float* __restrict__ out,
    ushort* __restrict__ outB) {
  __shared__ __align__(16) ushort Xt[64 * 136];
  __shared__ __align__(16) ushort Hs[64 * 264];
  __shared__ __align__(16) ushort Bb[8192];
  const int tid = threadIdx.x;
  const int n0 = blockIdx.x * 64;
  const int lane = tid & 63, wv = tid >> 6;
  const int c = lane & 15, g = lane >> 4, r0 = wv * 16;

  float xres[8][4];
#pragma unroll
  for (int t = 0; t < 8; ++t)
#pragma unroll
    for (int rr = 0; rr < 4; ++rr) {
      int row = n0 + r0 + g * 4 + rr;
      if (row > NN - 1) row = NN - 1;
      xres[t][rr] = xres_g[(size_t)row * DD + t * 16 + c];
    }
  uint4 w[4], wn[4];
#pragma unroll
  for (int i = 0; i < 2; ++i) {
    int u = tid + i * 256;
    w[i] = ldg16(WoT + (size_t)(u >> 2) * 128 + (u & 3) * 8);
  }
#pragma unroll
  for (int it = 0; it < 8; ++it) {
    int ch = it * 256 + tid, row = ch >> 5, j = ch & 31;
    int gr = n0 + row; if (gr > NN - 1) gr = NN - 1;
    float4 vv = *(const float4*)(vagg + (size_t)gr * DD + j * 4);
    ushort4 ov; ov.x = f2bf(vv.x); ov.y = f2bf(vv.y); ov.z = f2bf(vv.z); ov.w = f2bf(vv.w);
    *(ushort4*)(Xt + row * 136 + j * 4) = ov;
  }
  f32x4 acc0[8];
#pragma unroll
  for (int t = 0; t < 8; ++t) acc0[t] = (f32x4){0.f, 0.f, 0.f, 0.f};
  // ---- vagg @ Wo (4 phases) ----
#pragma unroll
  for (int kk = 0; kk < 4; ++kk) {
    __syncthreads();
#pragma unroll
    for (int i = 0; i < 2; ++i) *(uint4*)(Bb + (tid + i * 256) * 8) = w[i];
    if (kk < 3) {
#pragma unroll
      for (int i = 0; i < 2; ++i) {
        int u = tid + i * 256;
        wn[i] = ldg16(WoT + (size_t)(u >> 2) * 128 + (kk + 1) * 32 + (u & 3) * 8);
      }
    }
    __syncthreads();
    bf16x8 a = *(const bf16x8*)(Xt + (r0 + c) * 136 + kk * 32 + g * 8);
#pragma unroll
    for (int t = 0; t < 8; ++t)
      acc0[t] = __builtin_amdgcn_mfma_f32_16x16x32_bf16(
          a, *(const bf16x8*)(Bb + (t * 16 + c) * 32 + g * 8), acc0[t], 0, 0, 0);
#pragma unroll
    for (int i = 0; i < 2; ++i) w[i] = wn[i];
  }
  // ---- LN1 -> xmid ----
  {
    float s1[4] = {0, 0, 0, 0}, s2[4] = {0, 0, 0, 0};
#pragma unroll
    for (int t = 0; t < 8; ++t)
#pragma unroll
      for (int rr = 0; rr < 4; ++rr) {
        float s = acc0[t][rr] + xres[t][rr];
        acc0[t][rr] = s; s1[rr] += s; s2[rr] += s * s;
      }
    float mean[4], rstd[4];
#pragma unroll
    for (int rr = 0; rr < 4; ++rr) {
      red16_2(s1[rr], s2[rr]);
      mean[rr] = s1[rr] * (1.f / DD);
      rstd[rr] = rsqrtf(s2[rr] * (1.f / DD) - mean[rr] * mean[rr] + 1e-5f);
    }
#pragma unroll
    for (int t = 0; t < 8; ++t) {
      float gv = g1[t * 16 + c], tv = bt1[t * 16 + c];
#pragma unroll
      for (int rr = 0; rr < 4; ++rr) {
        float o = (acc0[t][rr] - mean[rr]) * rstd[rr] * gv + tv;
        Xt[(r0 + g * 4 + rr) * 136 + t * 16 + c] = f2bf(o);
      }
    }
  }
  // ---- h = relu(xmid @ W1 + b1) ----
  f32x4 acc16[16];
#pragma unroll
  for (int t = 0; t < 16; ++t) acc16[t] = (f32x4){0.f, 0.f, 0.f, 0.f};
#pragma unroll
  for (int i = 0; i < 4; ++i) {
    int u = tid + i * 256;
    w[i] = ldg16(W1T + (size_t)(u >> 2) * 128 + (u & 3) * 8);
  }
#pragma unroll
  for (int kk = 0; kk < 4; ++kk) {
    __syncthreads();
#pragma unroll
    for (int i = 0; i < 4; ++i) *(uint4*)(Bb + (tid + i * 256) * 8) = w[i];
    if (kk < 3) {
#pragma unroll
      for (int i = 0; i < 4; ++i) {
        int u = tid + i * 256;
        wn[i] = ldg16(W1T + (size_t)(u >> 2) * 128 + (kk + 1) * 32 + (u & 3) * 8);
      }
    }
    __syncthreads();
    bf16x8 a = *(const bf16x8*)(Xt + (r0 + c) * 136 + kk * 32 + g * 8);
#pragma unroll
    for (int t = 0; t < 16; ++t)
      acc16[t] = __builtin_amdgcn_mfma_f32_16x16x32_bf16(
          a, *(const bf16x8*)(Bb + (t * 16 + c) * 32 + g * 8), acc16[t], 0, 0, 0);
#pragma unroll
    for (int i = 0; i < 4; ++i) w[i] = wn[i];
  }
#pragma unroll
  for (int t = 0; t < 16; ++t) {
    float bv = b1[t * 16 + c];
#pragma unroll
    for (int rr = 0; rr < 4; ++rr)
      Hs[(r0 + g * 4 + rr) * 264 + t * 16 + c] = f2bf(fmaxf(acc16[t][rr] + bv, 0.f));
  }
  // ---- h @ W2 (8 phases) ----
#pragma unroll
  for (int t = 0; t < 8; ++t) acc0[t] = (f32x4){0.f, 0.f, 0.f, 0.f};
#pragma unroll
  for (int i = 0; i < 2; ++i) {
    int u = tid + i * 256;
    w[i] = ldg16(W2T + (size_t)(u >> 2) * 256 + (u & 3) * 8);
  }
#pragma unroll
  for (int kk = 0; kk < 8; ++kk) {
    __syncthreads();
#pragma unroll
    for (int i = 0; i < 2; ++i) *(uint4*)(Bb + (tid + i * 256) * 8) = w[i];
    if (kk < 7) {
#pragma unroll
      for (int i = 0; i < 2; ++i) {
        int u = tid + i * 256;
        wn[i] = ldg16(W2T + (size_t)(u >> 2) * 256 + (kk + 1) * 32 + (u & 3) * 8);
      }
    }
    __syncthreads();
    bf16x8 a = *(const bf16x8*)(Hs + (r0 + c) * 264 + kk * 32 + g * 8);
#pragma unroll
    for (int t = 0; t < 8; ++t)
      acc0[t] = __builtin_amdgcn_mfma_f32_16x16x32_bf16(
          a, *(const bf16x8*)(Bb + (t * 16 + c) * 32 + g * 8), acc0[t], 0, 0, 0);
#pragma unroll
    for (int i = 0; i < 2; ++i) w[i] = wn[i];
  }
  // ---- LN2 + stores ----
  {
    float s1[4] = {0, 0, 0, 0}, s2[4] = {0, 0, 0, 0};
#pragma unroll
    for (int t = 0; t < 8; ++t) {
      float bv = b2[t * 16 + c];
#pragma unroll
      for (int rr = 0; rr < 4; ++rr) {
        float s = acc0[t][rr] + bv + bf2f(Xt[(r0 + g * 4 + rr) * 136 + t * 16 + c]);
        acc0[t][rr] = s; s1[rr] += s; s2[rr] += s * s;
      }
    }
    float mean[4], rstd[4];
#pragma unroll
    for (int rr = 0; rr < 4; ++rr) {
      red16_2(s1[rr], s2[rr]);
      mean[rr] = s1[rr] * (1.f / DD);
      rstd[rr] = rsqrtf(s2[rr] * (1.f / DD) - mean[rr] * mean[rr] + 1e-5f);
    }
#pragma unroll
    for (int t = 0; t < 8; ++t) {
      float gv = g2[t * 16 + c], tv = bt2[t * 16 + c];
#pragma unroll
      for (int rr = 0; rr < 4; ++rr) {
        float o = (acc0[t][rr] - mean[rr]) * rstd[rr] * gv + tv;
        int row = n0 + r0 + g * 4 + rr;
        if (row < NN) out[(size_t)row * DD + t * 16 + c] = o;
        Xt[(r0 + g * 4 + rr) * 136 + t * 16 + c] = f2bf(o);
      }
    }
  }
  __syncthreads();
#pragma unroll
  for (int it = 0; it < 4; ++it) {
    int ch = it * 256 + tid, row = ch >> 4, j = ch & 15;
    int gr = n0 + row;
    if (gr < NN)
      *(uint4*)(outB + (size_t)gr * DD + j * 8) = *(const uint4*)(Xt + row * 136 + j * 8);
  }
}

extern "C" void kernel_launch(void* const* d_in, const int* in_sizes, int n_in,
                              void* d_out, int out_size, void* d_ws,
                              size_t ws_size, hipStream_t stream) {
  (void)in_sizes; (void)n_in; (void)out_size; (void)ws_size;
  const float* lane_feats = (const float*)d_in[0];
  const float* edge_attrs = (const float*)d_in[1];
  const int* ei = (const int*)d_in[2];
  const int* dst = ei + NE;
  const float* node_W = (const float*)d_in[3];
  const float* node_b = (const float*)d_in[4];
  const float* node_g = (const float*)d_in[5];
  const float* node_bt = (const float*)d_in[6];
  const float* rpe_W = (const float*)d_in[7];
  const float* rpe_b = (const float*)d_in[8];
  const float* rpe_g = (const float*)d_in[9];
  const float* rpe_bt = (const float*)d_in[10];
  const float* mem_W = (const float*)d_in[11];
  const float* mem_b = (const float*)d_in[12];
  const float* mem_g = (const float*)d_in[13];
  const float* mem_bt = (const float*)d_in[14];
  const float* Wq = (const float*)d_in[15];
  const float* Wk = (const float*)d_in[16];
  const float* Wv = (const float*)d_in[17];
  const float* Wo = (const float*)d_in[18];
  const float* eu_W = (const float*)d_in[19];
  const float* eu_b = (const float*)d_in[20];
  const float* eu_g = (const float*)d_in[21];
  const float* eu_bt = (const float*)d_in[22];
  const float* en_g = (const float*)d_in[23];
  const float* en_bt = (const float*)d_in[24];
  const float* ffn_W1 = (const float*)d_in[25];
  const float* ffn_b1 = (const float*)d_in[26];
  const float* ffn_W2 = (const float*)d_in[27];
  const float* ffn_b2 = (const float*)d_in[28];
  const float* n1_g = (const float*)d_in[29];
  const float* n1_bt = (const float*)d_in[30];
  const float* n2_g = (const float*)d_in[31];
  const float* n2_bt = (const float*)d_in[32];

  char* p = (char*)d_ws;
  auto alloc = [&](size_t bytes) -> char* {
    char* r = p; p += (bytes + 255) & ~(size_t)255; return r;
  };
  float* x = (float*)alloc((size_t)NN * DD * 4);
  float* vagg = (float*)alloc((size_t)NN * DD * 4);
  float* lg = (float*)alloc((size_t)NE * 8 * 4);
  float* Pa = (float*)alloc((size_t)NN * DD * 4);
  float* Pb = (float*)alloc((size_t)NN * DD * 4);
  ushort* qb = (ushort*)alloc((size_t)NN * DD * 2);
  ushort* xb = (ushort*)alloc((size_t)NN * DD * 2);
  ushort* eb = (ushort*)alloc((size_t)NE * DD * 2);
  ushort* vb = (ushort*)alloc((size_t)NE * DD * 2);
  ushort* memWT = (ushort*)alloc((size_t)NL * DD * 384 * 2);
  ushort* euWT = (ushort*)alloc((size_t)NL * DD * DD * 2);
  ushort* WqT = (ushort*)alloc((size_t)NL * DD * DD * 2);
  ushort* WkT = (ushort*)alloc((size_t)NL * DD * DD * 2);
  ushort* WvT = (ushort*)alloc((size_t)NL * DD * DD * 2);
  ushort* WoT = (ushort*)alloc((size_t)NL * DD * DD * 2);
  ushort* W1T = (ushort*)alloc((size_t)NL * 256 * DD * 2);
  ushort* W2T = (ushort*)alloc((size_t)NL * DD * 256 * 2);
  int* deg = (int*)alloc((size_t)NN * 4);
  int* rowptr = (int*)alloc((size_t)(NN + 1) * 4);
  int* cursor = (int*)alloc((size_t)NN * 4);
  int* eids = (int*)alloc((size_t)NE * 4);
  int* srcP = (int*)alloc((size_t)NE * 4);
  int* dstP = (int*)alloc((size_t)NE * 4);

  // CSR build + edge permutation (dst is layer-invariant)
  hipMemsetAsync(deg, 0, (size_t)NN * 4, stream);
  k_hist<<<NE / 256, 256, 0, stream>>>(dst, deg);
  k_scan<<<1, 256, 0, stream>>>(deg, rowptr, cursor);
  k_scatter<<<NE / 256, 256, 0, stream>>>(dst, cursor, eids);
  k_permidx<<<NE / 256, 256, 0, stream>>>(ei, eids, srcP, dstP);

  k_transp<<<dim3(12, 4, NL), 256, 0, stream>>>(mem_W, memWT, 384, DD);
  k_transp5<<<dim3(4, 4, 5 * NL), 256, 0, stream>>>(
      Wq, Wk, Wv, Wo, eu_W, WqT, WkT, WvT, WoT, euWT);
  k_transp<<<dim3(4, 8, NL), 256, 0, stream>>>(ffn_W1, W1T, DD, 256);
  k_transp<<<dim3(8, 4, NL), 256, 0, stream>>>(ffn_W2, W2T, 256, DD);

  k_inproj<10><<<NN / 4, 256, 0, stream>>>(lane_feats, nullptr, node_W, node_b,
                                           node_g, node_bt, x, xb, NN);
  // edge projection gathered into CSR order
  k_inproj<9><<<NE / 4, 256, 0, stream>>>(edge_attrs, eids, rpe_W, rpe_b,
                                          rpe_g, rpe_bt, nullptr, eb, NE);

  const int NB = (NN + 63) / 64;
  for (int l = 0; l < NL; ++l) {
    k_nodepre<<<dim3(NB, 3), 256, 0, stream>>>(
        xb, memWT + (size_t)l * DD * 384, WqT + (size_t)l * DD * DD,
        mem_b + l * DD, Pa, Pb, qb);
    k_edge<<<NE / 64, 256, 0, stream>>>(
        eb, vb, Pa, Pb, qb, srcP, dstP, memWT + (size_t)l * DD * 384,
        mem_g + l * DD, mem_bt + l * DD, euWT + (size_t)l * DD * DD,
        eu_b + l * DD, eu_g + l * DD, eu_bt + l * DD, en_g + l * DD,
        en_bt + l * DD, WkT + (size_t)l * DD * DD, WvT + (size_t)l * DD * DD,
        lg);
    k_aggr<<<(NN + 3) / 4, 256, 0, stream>>>(vb, lg, rowptr, vagg);
    k_node2<<<NB, 256, 0, stream>>>(
        vagg, WoT + (size_t)l * DD * DD, x, n1_g + l * DD, n1_bt + l * DD,
        W1T + (size_t)l * 256 * DD, ffn_b1 + l * 256,
        W2T + (size_t)l * DD * 256, ffn_b2 + l * DD, n2_g + l * DD,
        n2_bt + l * DD, (l == NL - 1) ? (float*)d_out : x, xb);
  }
}